// Round 7
// baseline (254.175 us; speedup 1.0000x reference)
//
#include <hip/hip_runtime.h>
#include <hip/hip_bf16.h>

#define H_DIM 1024
#define E_NUM 8
#define F_DIM 2048
#define N_TOK 2048   // B*S
typedef unsigned int uint;
typedef short bf16x8 __attribute__((ext_vector_type(8)));
typedef float f32x4 __attribute__((ext_vector_type(4)));

// ws layout (total ~25.3 MB)
#define WS_CNT   0
#define WS_LIST  256                       // int[8*2048]
#define WS_W     (WS_LIST + 8*N_TOK*4)     // float[4096]
#define WS_G     131072                    // bf16 [4096][2048] = 16 MB (k-PERMUTED rows)
#define WS_Y     (WS_G + 4096*2048*2)      // bf16 [4096][1024] = 8 MB
#define WS_XB    WS_Y                      // bf16 x [2048][1024] (k-PERMUTED), dead before y written

// Row k-permutation: storage position of element k is
//   pi(k) = ((k>>5)*4 + ((k>>2)&3))*8 + ((k>>4)&1)*4 + (k&3)
// block-local to every 64-k step; each 16B chunk is one MFMA A-fragment k-set.

static __device__ __forceinline__ uint f2bf(float f) {
    uint u = __builtin_bit_cast(uint, f);
    return (u + 0x7FFFu + ((u >> 16) & 1u)) >> 16;   // RNE
}
static __device__ __forceinline__ float bflo(uint u) { return __builtin_bit_cast(float, u << 16); }
static __device__ __forceinline__ float bfhi(uint u) { return __builtin_bit_cast(float, u & 0xFFFF0000u); }
static __device__ __forceinline__ uint cvtpk(float a, float b) {
    uint r;
    asm("v_cvt_pk_bf16_f32 %0, %1, %2" : "=v"(r) : "v"(a), "v"(b));  // a->low16, b->high16
    return r;
}
static __device__ __forceinline__ void gload_lds16(const void* g, void* l) {
    __builtin_amdgcn_global_load_lds(
        (const __attribute__((address_space(1))) unsigned int*)g,
        (__attribute__((address_space(3))) unsigned int*)l,
        16, 0, 0);
}
template<int N> static __device__ __forceinline__ void vmwait() {
    if constexpr (N == 0)       asm volatile("s_waitcnt vmcnt(0)" ::: "memory");
    else if constexpr (N == 10) asm volatile("s_waitcnt vmcnt(10)" ::: "memory");
}

// ---------------- x -> bf16, k-permuted ----------------
__global__ __launch_bounds__(256) void cvt_x_kernel(const float* __restrict__ x,
                                                    unsigned short* __restrict__ xb)
{
    int c = blockIdx.x * 256 + threadIdx.x;
    int row = c >> 7, b = c & 127;
    int t = b >> 3, s = b & 7;
    int klo = t*64 + (s >> 2)*32 + (s & 3)*4;
    const float* xr = x + (size_t)row * H_DIM;
    float4 lo = *(const float4*)(xr + klo);
    float4 hi = *(const float4*)(xr + klo + 16);
    uint4 o;
    o.x = cvtpk(lo.x, lo.y); o.y = cvtpk(lo.z, lo.w);
    o.z = cvtpk(hi.x, hi.y); o.w = cvtpk(hi.z, hi.w);
    *(uint4*)(xb + (size_t)row * H_DIM + b*8) = o;
}

// ---------------- router ----------------
__global__ __launch_bounds__(256) void router_kernel(
    const float* __restrict__ x, const float* __restrict__ rw,
    int* __restrict__ cnt, int* __restrict__ list, float* __restrict__ w_entry)
{
    int wave = threadIdx.x >> 6, lane = threadIdx.x & 63;
    int n = blockIdx.x * 4 + wave;
    const float* xr = x + (size_t)n * H_DIM;
    float acc[8] = {0,0,0,0,0,0,0,0};
    #pragma unroll
    for (int i = 0; i < H_DIM/64; ++i) {
        int h = i*64 + lane;
        float xv = xr[h];
        const float4* rr = (const float4*)(rw + (size_t)h*8);
        float4 r0 = rr[0], r1 = rr[1];
        acc[0] += xv*r0.x; acc[1] += xv*r0.y; acc[2] += xv*r0.z; acc[3] += xv*r0.w;
        acc[4] += xv*r1.x; acc[5] += xv*r1.y; acc[6] += xv*r1.z; acc[7] += xv*r1.w;
    }
    #pragma unroll
    for (int e = 0; e < 8; ++e) {
        float v = acc[e];
        #pragma unroll
        for (int off = 32; off; off >>= 1) v += __shfl_xor(v, off);
        acc[e] = v;
    }
    int e0 = 0;
    #pragma unroll
    for (int e = 1; e < 8; ++e) if (acc[e] > acc[e0]) e0 = e;
    int e1 = -1;
    #pragma unroll
    for (int e = 0; e < 8; ++e) if (e != e0 && (e1 < 0 || acc[e] > acc[e1])) e1 = e;
    float w0 = 1.0f / (1.0f + __expf(acc[e1] - acc[e0]));
    float w1 = 1.0f - w0;
    if (lane == 0) {
        int p0 = atomicAdd(&cnt[e0], 1);
        list[e0*N_TOK + p0] = n*2;
        w_entry[n*2] = w0;
        int p1 = atomicAdd(&cnt[e1], 1);
        list[e1*N_TOK + p1] = n*2 + 1;
        w_entry[n*2+1] = w1;
    }
}

// ---------------- fused expert GEMM (counted-vmcnt zero-drain pipeline) ----------------
// 64x128 tile, BK=64, 4 waves col-split. A: bf16 k-permuted via glds (verified map).
// B: fp32 via glds into ((k&12)<<4)-XOR-swizzled LDS (source pre-swizzled), cvt at
// fragment read. No ds_write, no vmcnt(0) in loop, raw barriers + vmcnt(10).
template<int IS_G1>
__global__ __launch_bounds__(256, 2) void moe_gemm_kernel(
    const unsigned short* __restrict__ Asrc, const float* __restrict__ W,
    const int* __restrict__ cnt, const int* __restrict__ list,
    const float* __restrict__ w_entry, unsigned short* __restrict__ dst)
{
    constexpr int KTOT  = IS_G1 ? H_DIM : F_DIM;
    constexpr int BLD   = IS_G1 ? 2*F_DIM : H_DIM;   // W row stride (fp32)
    constexpr int DLD   = IS_G1 ? F_DIM : H_DIM;     // dst row stride
    constexpr int ALD   = IS_G1 ? H_DIM : F_DIM;     // A src row stride (shorts)
    constexpr int NMT   = 32;
    constexpr int NNT   = IS_G1 ? 32 : 8;
    constexpr int NT    = KTOT / 64;

    __shared__ __align__(16) unsigned short As[2][64*64];   // 2 x 8 KB
    __shared__ __align__(16) uint Bs[2][64*128];            // 2 x 32 KB fp32 [k][128c] swz

    constexpr int nb = NMT * NNT * E_NUM;
    constexpr int chunk = nb >> 3;
    int bid = blockIdx.x;
    int f  = (bid & 7) * chunk + (bid >> 3);
    int mt = f % NMT;
    int nt = (f / NMT) % NNT;
    int e  = f / (NMT * NNT);

    const int c = cnt[e];
    if (mt * 64 >= c) return;
    const int tid = threadIdx.x;
    const int lane = tid & 63, wid = tid >> 6;
    const int l15 = lane & 15, lg = lane >> 4;
    const int lbase = e * N_TOK + mt * 64;

    // A staging sources (pre-swizzled: linear glds dest == bank-swizzled layout)
    const unsigned short* a_src[2];
    #pragma unroll
    for (int i = 0; i < 2; ++i) {
        int sl  = wid*2048 + i*1024 + lane*16;
        int row = sl >> 7;
        int kb  = ((sl >> 4) & 7) ^ (row & 7);
        int rr  = (mt*64 + row) < c ? row : (c - 1 - mt*64);
        int ent = list[lbase + rr];
        int arow = IS_G1 ? (ent >> 1) : ent;
        a_src[i] = Asrc + (size_t)arow * ALD + kb*8;
    }

    // B staging sources: wave w covers k rows w*16..+15; chunk i: k = w*16+i*2+(lane>>5),
    // col4 = (lane&31) ^ (k&12)  [inverse of LDS byte swizzle ((k&12)<<4)]
    const float* Wb = W + (size_t)e * (size_t)(IS_G1 ? H_DIM*2*F_DIM : F_DIM*H_DIM);
    const float* b_srcp[8];
    #pragma unroll
    for (int i = 0; i < 8; ++i) {
        int k  = wid*16 + i*2 + (lane >> 5);
        int c4 = (lane & 31) ^ (k & 12);
        int gc;
        if constexpr (IS_G1) gc = (c4 < 16) ? (nt*64 + 4*c4) : (F_DIM + nt*64 + 4*(c4-16));
        else                 gc = nt*128 + 4*c4;
        b_srcp[i] = Wb + (size_t)k * BLD + gc;
    }

    // fragment addresses
    int a_addr[4][2];
    #pragma unroll
    for (int m = 0; m < 4; ++m)
        #pragma unroll
        for (int kk = 0; kk < 2; ++kk) {
            int row = m*16 + l15;
            a_addr[m][kk] = row*128 + ((kk*64 + lg*16) ^ ((row & 7) << 4));
        }
    int b_base[2];
    #pragma unroll
    for (int j = 0; j < 2; ++j) {
        int cb = j ? (4 + wid) : wid;                 // cols cb*16+l15
        b_base[j] = ((cb*16 + l15) * 4) ^ (lg << 6);  // byte ^ matches src swizzle
    }

    f32x4 acc[4][2];
    #pragma unroll
    for (int m = 0; m < 4; ++m)
        #pragma unroll
        for (int j = 0; j < 2; ++j) acc[m][j] = (f32x4){0.f,0.f,0.f,0.f};

    auto STAGE = [&](int tt) {
        const int b = tt & 1;
        #pragma unroll
        for (int i = 0; i < 2; ++i)
            gload_lds16(a_src[i] + tt*64, (char*)As[b] + wid*2048 + i*1024);
        #pragma unroll
        for (int i = 0; i < 8; ++i)
            gload_lds16(b_srcp[i] + (size_t)tt * 64 * BLD, (char*)Bs[b] + wid*8192 + i*1024);
    };

    auto compute_step = [&](const char* ab, const char* bb0) {
        #pragma unroll
        for (int kk = 0; kk < 2; ++kk) {
            bf16x8 af[4];
            #pragma unroll
            for (int m = 0; m < 4; ++m)
                af[m] = *(const bf16x8*)(ab + a_addr[m][kk]);
            bf16x8 bfr[2];
            #pragma unroll
            for (int j = 0; j < 2; ++j) {
                const char* bb = bb0 + (kk*32 + 4*lg)*512 + b_base[j];
                float fA0 = *(const float*)(bb);
                float fA1 = *(const float*)(bb + 512);
                float fA2 = *(const float*)(bb + 1024);
                float fA3 = *(const float*)(bb + 1536);
                float fB0 = *(const float*)(bb + 8192);
                float fB1 = *(const float*)(bb + 8192 + 512);
                float fB2 = *(const float*)(bb + 8192 + 1024);
                float fB3 = *(const float*)(bb + 8192 + 1536);
                union { uint u[4]; bf16x8 v; } bu;
                bu.u[0] = cvtpk(fA0, fA1);
                bu.u[1] = cvtpk(fA2, fA3);
                bu.u[2] = cvtpk(fB0, fB1);
                bu.u[3] = cvtpk(fB2, fB3);
                bfr[j] = bu.v;
            }
            #pragma unroll
            for (int m = 0; m < 4; ++m)
                #pragma unroll
                for (int j = 0; j < 2; ++j)
                    acc[m][j] = __builtin_amdgcn_mfma_f32_16x16x32_bf16(af[m], bfr[j], acc[m][j], 0, 0, 0);
        }
    };

    // ---- prologue: stage t=0,1 (20 glds in flight per wave) ----
    STAGE(0);
    STAGE(1);

    // ---- main loop: zero-drain counted pipeline ----
    #pragma unroll
    for (int t = 0; t < NT; ++t) {
        if (t < NT - 1) vmwait<10>();   // own stage(t) landed; stage(t+1) stays in flight
        else            vmwait<0>();    // last tile: drain
        __builtin_amdgcn_sched_barrier(0);
        __builtin_amdgcn_s_barrier();   // all waves' stage(t) complete
        asm volatile("" ::: "memory");
        compute_step((const char*)As[t & 1], (const char*)Bs[t & 1]);
        if (t + 2 < NT) {
            asm volatile("" ::: "memory");
            __builtin_amdgcn_s_barrier();   // all waves done reading buffer t&1
            asm volatile("" ::: "memory");
            STAGE(t + 2);                   // refill the buffer just consumed
        }
    }

    // ---- epilogue ----
    if constexpr (IS_G1) {
        // g F-col for this wave: gate f0 = nt*64 + wid*16 + l15 (value at +F).
        // k-PERMUTED store pos = nt*64 + ((wid>>1)*4 + (l15>>2))*8 + (wid&1)*4 + (l15&3)
        const int pbase = nt*64 + ((wid >> 1)*4 + (l15 >> 2))*8 + (wid & 1)*4 + (l15 & 3);
        #pragma unroll
        for (int m = 0; m < 4; ++m) {
            f32x4 ga = acc[m][0], gv = acc[m][1];
            #pragma unroll
            for (int i = 0; i < 4; ++i) {
                int rl = m*16 + lg*4 + i;
                if (mt*64 + rl < c) {
                    int ent = list[lbase + rl];
                    float a = ga[i];
                    float g = (a / (1.f + __expf(-a))) * gv[i];
                    dst[(size_t)ent * DLD + pbase] = (unsigned short)f2bf(g);
                }
            }
        }
    } else {
        #pragma unroll
        for (int m = 0; m < 4; ++m)
            #pragma unroll
            for (int i = 0; i < 4; ++i) {
                int rl = m*16 + lg*4 + i;
                if (mt*64 + rl < c) {
                    int ent = list[lbase + rl];
                    float w = w_entry[ent];
                    #pragma unroll
                    for (int j = 0; j < 2; ++j) {
                        int col = nt*128 + (j ? (64 + wid*16) : (wid*16)) + l15;
                        dst[(size_t)ent * DLD + col] = (unsigned short)f2bf(w * acc[m][j][i]);
                    }
                }
            }
    }
}

// ---------------- combine ----------------
__global__ __launch_bounds__(256) void combine_kernel(
    const unsigned short* __restrict__ y, float* __restrict__ out)
{
    int gid = blockIdx.x * 256 + threadIdx.x;
    size_t base = (size_t)gid * 8;
    int n = (int)(base >> 10), h = (int)(base & 1023);
    const uint4 a = *(const uint4*)(y + (size_t)(2*n)   * 1024 + h);
    const uint4 b = *(const uint4*)(y + (size_t)(2*n+1) * 1024 + h);
    float4 o0, o1;
    o0.x = bflo(a.x)+bflo(b.x); o0.y = bfhi(a.x)+bfhi(b.x);
    o0.z = bflo(a.y)+bflo(b.y); o0.w = bfhi(a.y)+bfhi(b.y);
    o1.x = bflo(a.z)+bflo(b.z); o1.y = bfhi(a.z)+bfhi(b.z);
    o1.z = bflo(a.w)+bflo(b.w); o1.w = bfhi(a.w)+bfhi(b.w);
    *(float4*)(out + base)     = o0;
    *(float4*)(out + base + 4) = o1;
}

extern "C" void kernel_launch(void* const* d_in, const int* in_sizes, int n_in,
                              void* d_out, int out_size, void* d_ws, size_t ws_size,
                              hipStream_t stream) {
    const float* x  = (const float*)d_in[0];
    const float* rw = (const float*)d_in[1];
    const float* W1 = (const float*)d_in[2];
    const float* W2 = (const float*)d_in[3];
    float* out = (float*)d_out;
    char* ws = (char*)d_ws;
    int*   cnt     = (int*)(ws + WS_CNT);
    int*   list    = (int*)(ws + WS_LIST);
    float* w_entry = (float*)(ws + WS_W);
    unsigned short* g  = (unsigned short*)(ws + WS_G);
    unsigned short* y  = (unsigned short*)(ws + WS_Y);
    unsigned short* xb = (unsigned short*)(ws + WS_XB);

    hipMemsetAsync(cnt, 0, E_NUM * sizeof(int), stream);
    cvt_x_kernel<<<N_TOK*H_DIM/2048, 256, 0, stream>>>(x, xb);
    router_kernel<<<N_TOK/4, 256, 0, stream>>>(x, rw, cnt, list, w_entry);
    moe_gemm_kernel<1><<<32*32*E_NUM, 256, 0, stream>>>(xb, W1, cnt, list, w_entry, g);
    moe_gemm_kernel<0><<<32*8*E_NUM, 256, 0, stream>>>(g,  W2, cnt, list, w_entry, y);
    combine_kernel<<<(out_size/8 + 255)/256, 256, 0, stream>>>(y, out);
}

// Round 8
// 237.428 us; speedup vs baseline: 1.0705x; 1.0705x over previous
//
#include <hip/hip_runtime.h>
#include <hip/hip_bf16.h>

#define H_DIM 1024
#define E_NUM 8
#define F_DIM 2048
#define N_TOK 2048   // B*S
typedef unsigned int uint;
typedef short bf16x8 __attribute__((ext_vector_type(8)));
typedef float f32x4 __attribute__((ext_vector_type(4)));

// ws layout (total ~25.3 MB)
#define WS_CNT   0
#define WS_LIST  256                       // int[8*2048]
#define WS_W     (WS_LIST + 8*N_TOK*4)     // float[4096]
#define WS_G     131072                    // bf16 [4096][2048] = 16 MB (k-PERMUTED rows)
#define WS_Y     (WS_G + 4096*2048*2)      // bf16 [4096][1024] = 8 MB
#define WS_XB    WS_Y                      // bf16 x [2048][1024] (k-PERMUTED), dead before y written

// Row k-permutation: storage position of element k is
//   pi(k) = ((k>>5)*4 + ((k>>2)&3))*8 + ((k>>4)&1)*4 + (k&3)
// block-local to every 64-k step; each 16B chunk is one MFMA A-fragment k-set.

static __device__ __forceinline__ uint f2bf(float f) {
    uint u = __builtin_bit_cast(uint, f);
    return (u + 0x7FFFu + ((u >> 16) & 1u)) >> 16;   // RNE
}
static __device__ __forceinline__ float bflo(uint u) { return __builtin_bit_cast(float, u << 16); }
static __device__ __forceinline__ float bfhi(uint u) { return __builtin_bit_cast(float, u & 0xFFFF0000u); }
static __device__ __forceinline__ uint cvtpk(float a, float b) {
    uint r;
    asm("v_cvt_pk_bf16_f32 %0, %1, %2" : "=v"(r) : "v"(a), "v"(b));  // a->low16, b->high16
    return r;
}
static __device__ __forceinline__ void gload_lds16(const void* g, void* l) {
    __builtin_amdgcn_global_load_lds(
        (const __attribute__((address_space(1))) unsigned int*)g,
        (__attribute__((address_space(3))) unsigned int*)l,
        16, 0, 0);
}
template<int N> static __device__ __forceinline__ void vmwait() {
    if constexpr (N == 0)      asm volatile("s_waitcnt vmcnt(0)" ::: "memory");
    else if constexpr (N == 4) asm volatile("s_waitcnt vmcnt(4)" ::: "memory");
    else if constexpr (N == 5) asm volatile("s_waitcnt vmcnt(5)" ::: "memory");
    else if constexpr (N == 6) asm volatile("s_waitcnt vmcnt(6)" ::: "memory");
}

// ---------------- x -> bf16, k-permuted ----------------
__global__ __launch_bounds__(256) void cvt_x_kernel(const float* __restrict__ x,
                                                    unsigned short* __restrict__ xb)
{
    int c = blockIdx.x * 256 + threadIdx.x;
    int row = c >> 7, b = c & 127;
    int t = b >> 3, s = b & 7;
    int klo = t*64 + (s >> 2)*32 + (s & 3)*4;
    const float* xr = x + (size_t)row * H_DIM;
    float4 lo = *(const float4*)(xr + klo);
    float4 hi = *(const float4*)(xr + klo + 16);
    uint4 o;
    o.x = cvtpk(lo.x, lo.y); o.y = cvtpk(lo.z, lo.w);
    o.z = cvtpk(hi.x, hi.y); o.w = cvtpk(hi.z, hi.w);
    *(uint4*)(xb + (size_t)row * H_DIM + b*8) = o;
}

// ---------------- router ----------------
__global__ __launch_bounds__(256) void router_kernel(
    const float* __restrict__ x, const float* __restrict__ rw,
    int* __restrict__ cnt, int* __restrict__ list, float* __restrict__ w_entry)
{
    int wave = threadIdx.x >> 6, lane = threadIdx.x & 63;
    int n = blockIdx.x * 4 + wave;
    const float* xr = x + (size_t)n * H_DIM;
    float acc[8] = {0,0,0,0,0,0,0,0};
    #pragma unroll
    for (int i = 0; i < H_DIM/64; ++i) {
        int h = i*64 + lane;
        float xv = xr[h];
        const float4* rr = (const float4*)(rw + (size_t)h*8);
        float4 r0 = rr[0], r1 = rr[1];
        acc[0] += xv*r0.x; acc[1] += xv*r0.y; acc[2] += xv*r0.z; acc[3] += xv*r0.w;
        acc[4] += xv*r1.x; acc[5] += xv*r1.y; acc[6] += xv*r1.z; acc[7] += xv*r1.w;
    }
    #pragma unroll
    for (int e = 0; e < 8; ++e) {
        float v = acc[e];
        #pragma unroll
        for (int off = 32; off; off >>= 1) v += __shfl_xor(v, off);
        acc[e] = v;
    }
    int e0 = 0;
    #pragma unroll
    for (int e = 1; e < 8; ++e) if (acc[e] > acc[e0]) e0 = e;
    int e1 = -1;
    #pragma unroll
    for (int e = 0; e < 8; ++e) if (e != e0 && (e1 < 0 || acc[e] > acc[e1])) e1 = e;
    float w0 = 1.0f / (1.0f + __expf(acc[e1] - acc[e0]));
    float w1 = 1.0f - w0;
    if (lane == 0) {
        int p0 = atomicAdd(&cnt[e0], 1);
        list[e0*N_TOK + p0] = n*2;
        w_entry[n*2] = w0;
        int p1 = atomicAdd(&cnt[e1], 1);
        list[e1*N_TOK + p1] = n*2 + 1;
        w_entry[n*2+1] = w1;
    }
}

// ---------------- fused expert GEMM (counted-vmcnt, BK=32 B / BK=64 A) ----------------
// G1: 64x128 tile (4 waves: gate blk wid + value blk 4+wid). G2: 32x128 (wave blks wid*2+j).
// A bf16 k-permuted via glds (double-buffered per 64k). B fp32 via glds into
// ((k&12)<<4)-XOR LDS (source pre-swizzled), double-buffered per 32k, cvt at read.
// Waits: even step vmcnt(4), odd vmcnt(4+NA), never 0 in-loop. Coalesced epilogues.
template<int IS_G1>
__global__ __launch_bounds__(256, IS_G1 ? 3 : 4) void moe_gemm_kernel(
    const unsigned short* __restrict__ Asrc, const float* __restrict__ W,
    const int* __restrict__ cnt, const int* __restrict__ list,
    const float* __restrict__ w_entry, unsigned short* __restrict__ dst)
{
    constexpr int KTOT  = IS_G1 ? H_DIM : F_DIM;
    constexpr int BLD   = IS_G1 ? 2*F_DIM : H_DIM;   // W row stride (fp32)
    constexpr int DLD   = IS_G1 ? F_DIM : H_DIM;     // dst row stride
    constexpr int ALD   = IS_G1 ? H_DIM : F_DIM;     // A src row stride (shorts)
    constexpr int ROWS  = IS_G1 ? 64 : 32;
    constexpr int NM    = ROWS / 16;
    constexpr int NA    = ROWS / 32;                 // A glds per wave per 64k tile
    constexpr int NMT   = 2048 / ROWS;
    constexpr int NNT   = IS_G1 ? 32 : 8;
    constexpr int NT    = KTOT / 32;                 // 32-k steps
    constexpr int ODDW  = 4 + NA;

    __shared__ __align__(16) unsigned short As[2][ROWS*64];  // 2 x ROWS*128B
    __shared__ __align__(16) uint Bs[2][32*128];             // 2 x 16 KB fp32 [32k][128c] swz

    constexpr int nb = NMT * NNT * E_NUM;
    constexpr int chunk = nb >> 3;
    int bid = blockIdx.x;
    int f  = (bid & 7) * chunk + (bid >> 3);
    int mt = f % NMT;
    int nt = (f / NMT) % NNT;
    int e  = f / (NMT * NNT);

    const int c = cnt[e];
    if (mt * ROWS >= c) return;
    const int tid = threadIdx.x;
    const int lane = tid & 63, wid = tid >> 6;
    const int l15 = lane & 15, lg = lane >> 4;
    const int lbase = e * N_TOK + mt * ROWS;

    // A staging sources (pre-swizzled: linear glds dest == bank-swizzled layout)
    const unsigned short* a_src[NA];
    #pragma unroll
    for (int i = 0; i < NA; ++i) {
        int sl  = wid*(NA*1024) + i*1024 + lane*16;
        int row = sl >> 7;
        int kb  = ((sl >> 4) & 7) ^ (row & 7);
        int rr  = (mt*ROWS + row) < c ? row : (c - 1 - mt*ROWS);
        int ent = list[lbase + rr];
        int arow = IS_G1 ? (ent >> 1) : ent;
        a_src[i] = Asrc + (size_t)arow * ALD + kb*8;
    }

    // B staging: wave w covers k rows w*8..+7 per 32k step; src col4 pre-XOR'd by (k&12)
    const float* Wb = W + (size_t)e * (size_t)(IS_G1 ? H_DIM*2*F_DIM : F_DIM*H_DIM);
    const float* b_srcp[4];
    #pragma unroll
    for (int i = 0; i < 4; ++i) {
        int k  = wid*8 + i*2 + (lane >> 5);
        int c4 = (lane & 31) ^ (k & 12);
        int gc;
        if constexpr (IS_G1) gc = (c4 < 16) ? (nt*64 + 4*c4) : (F_DIM + nt*64 + 4*(c4-16));
        else                 gc = nt*128 + 4*c4;
        b_srcp[i] = Wb + (size_t)k * BLD + gc;
    }

    // fragment addresses
    int a_addr[NM][2];
    #pragma unroll
    for (int m = 0; m < NM; ++m)
        #pragma unroll
        for (int p = 0; p < 2; ++p) {
            int row = m*16 + l15;
            a_addr[m][p] = row*128 + ((p*64 + lg*16) ^ ((row & 7) << 4));
        }
    int b_base[2];
    #pragma unroll
    for (int j = 0; j < 2; ++j) {
        int cb = IS_G1 ? (j ? (4 + wid) : wid) : (wid*2 + j);
        b_base[j] = ((cb*16 + l15) * 4) ^ (lg << 6);
    }

    f32x4 acc[NM][2];
    #pragma unroll
    for (int m = 0; m < NM; ++m)
        #pragma unroll
        for (int j = 0; j < 2; ++j) acc[m][j] = (f32x4){0.f,0.f,0.f,0.f};

    auto STAGE_A = [&](int s) {
        #pragma unroll
        for (int i = 0; i < NA; ++i)
            gload_lds16(a_src[i] + s*64, (char*)As[s & 1] + wid*(NA*1024) + i*1024);
    };
    auto STAGE_B = [&](int t) {
        #pragma unroll
        for (int i = 0; i < 4; ++i)
            gload_lds16(b_srcp[i] + (size_t)t * 32 * BLD, (char*)Bs[t & 1] + wid*4096 + i*1024);
    };
    auto compute = [&](int P, int abuf) {   // P literal 0/1 at call sites
        const char* ab  = (const char*)As[abuf];
        const char* bb0 = (const char*)Bs[P];
        bf16x8 af[NM];
        #pragma unroll
        for (int m = 0; m < NM; ++m)
            af[m] = *(const bf16x8*)(ab + (P ? a_addr[m][1] : a_addr[m][0]));
        bf16x8 bfr[2];
        #pragma unroll
        for (int j = 0; j < 2; ++j) {
            const char* bb = bb0 + (4*lg)*512 + b_base[j];
            float fA0 = *(const float*)(bb);
            float fA1 = *(const float*)(bb + 512);
            float fA2 = *(const float*)(bb + 1024);
            float fA3 = *(const float*)(bb + 1536);
            float fB0 = *(const float*)(bb + 8192);
            float fB1 = *(const float*)(bb + 8192 + 512);
            float fB2 = *(const float*)(bb + 8192 + 1024);
            float fB3 = *(const float*)(bb + 8192 + 1536);
            union { uint u[4]; bf16x8 v; } bu;
            bu.u[0] = cvtpk(fA0, fA1);
            bu.u[1] = cvtpk(fA2, fA3);
            bu.u[2] = cvtpk(fB0, fB1);
            bu.u[3] = cvtpk(fB2, fB3);
            bfr[j] = bu.v;
        }
        #pragma unroll
        for (int m = 0; m < NM; ++m)
            #pragma unroll
            for (int j = 0; j < 2; ++j)
                acc[m][j] = __builtin_amdgcn_mfma_f32_16x16x32_bf16(af[m], bfr[j], acc[m][j], 0, 0, 0);
    };

    // ---- prologue ----
    STAGE_A(0); STAGE_B(0); STAGE_B(1);

    // ---- main loop: pairs of 32k steps, counted waits, no vmcnt(0) ----
    for (int tp = 0; tp < NT/2 - 1; ++tp) {
        const int t = 2*tp, ab = tp & 1;
        vmwait<4>();                     // A(tp), B(t) landed; B(t+1) in flight
        __builtin_amdgcn_sched_barrier(0);
        __builtin_amdgcn_s_barrier();
        asm volatile("" ::: "memory");
        compute(0, ab);
        asm volatile("" ::: "memory");
        __builtin_amdgcn_s_barrier();
        asm volatile("" ::: "memory");
        STAGE_A(tp + 1);
        STAGE_B(t + 2);
        vmwait<ODDW>();                  // B(t+1) landed; A(tp+1), B(t+2) in flight
        __builtin_amdgcn_sched_barrier(0);
        __builtin_amdgcn_s_barrier();
        asm volatile("" ::: "memory");
        compute(1, ab);
        asm volatile("" ::: "memory");
        __builtin_amdgcn_s_barrier();
        asm volatile("" ::: "memory");
        STAGE_B(t + 3);
    }
    // ---- final pair ----
    {
        const int ab = (NT/2 - 1) & 1;
        vmwait<4>();
        __builtin_amdgcn_sched_barrier(0);
        __builtin_amdgcn_s_barrier();
        asm volatile("" ::: "memory");
        compute(0, ab);
        asm volatile("" ::: "memory");
        vmwait<0>();
        __builtin_amdgcn_sched_barrier(0);
        __builtin_amdgcn_s_barrier();
        asm volatile("" ::: "memory");
        compute(1, ab);
    }

    // ---- epilogue (coalesced via LDS transpose; As/Bs[0] are dead) ----
    if constexpr (IS_G1) {
        unsigned short (*tb)[64] = (unsigned short (*)[64])As;  // 64x64 bf16 = 8 KB
        const int pcol = ((wid >> 1)*4 + (l15 >> 2))*8 + (wid & 1)*4 + (l15 & 3);
        #pragma unroll
        for (int m = 0; m < NM; ++m) {
            f32x4 ga = acc[m][0], gv = acc[m][1];
            #pragma unroll
            for (int i = 0; i < 4; ++i) {
                int row = m*16 + lg*4 + i;
                float a = ga[i];
                tb[row][pcol] = (unsigned short)f2bf((a / (1.f + __expf(-a))) * gv[i]);
            }
        }
        __syncthreads();
        int r = tid >> 3, ch = tid & 7;
        #pragma unroll
        for (int h = 0; h < 2; ++h) {
            int rr = r + h*32;
            if (mt*64 + rr < c) {
                int ent = list[lbase + rr];
                uint4 v = *(const uint4*)&tb[rr][ch*8];
                *(uint4*)((char*)dst + ((size_t)ent * DLD + nt*64)*2 + ch*16) = v;
            }
        }
    } else {
        float (*tb)[128] = (float (*)[128])Bs;   // 32x128 f32 = 16 KB
        #pragma unroll
        for (int m = 0; m < NM; ++m)
            #pragma unroll
            for (int j = 0; j < 2; ++j)
                #pragma unroll
                for (int i = 0; i < 4; ++i) {
                    int row = m*16 + lg*4 + i;
                    tb[row][(wid*2 + j)*16 + l15] = acc[m][j][i];
                }
        __syncthreads();
        int r = tid >> 3, ch = tid & 7;
        if (mt*32 + r < c) {
            int ent = list[lbase + r];
            float w = w_entry[ent];
            const float* src = &tb[r][ch*16];
            uint4 o0, o1;
            o0.x = cvtpk(w*src[0],  w*src[1]);  o0.y = cvtpk(w*src[2],  w*src[3]);
            o0.z = cvtpk(w*src[4],  w*src[5]);  o0.w = cvtpk(w*src[6],  w*src[7]);
            o1.x = cvtpk(w*src[8],  w*src[9]);  o1.y = cvtpk(w*src[10], w*src[11]);
            o1.z = cvtpk(w*src[12], w*src[13]); o1.w = cvtpk(w*src[14], w*src[15]);
            char* dp = (char*)dst + ((size_t)ent * DLD + nt*128 + ch*16)*2;
            *(uint4*)(dp)      = o0;
            *(uint4*)(dp + 16) = o1;
        }
    }
}

// ---------------- combine ----------------
__global__ __launch_bounds__(256) void combine_kernel(
    const unsigned short* __restrict__ y, float* __restrict__ out)
{
    int gid = blockIdx.x * 256 + threadIdx.x;
    size_t base = (size_t)gid * 8;
    int n = (int)(base >> 10), h = (int)(base & 1023);
    const uint4 a = *(const uint4*)(y + (size_t)(2*n)   * 1024 + h);
    const uint4 b = *(const uint4*)(y + (size_t)(2*n+1) * 1024 + h);
    float4 o0, o1;
    o0.x = bflo(a.x)+bflo(b.x); o0.y = bfhi(a.x)+bfhi(b.x);
    o0.z = bflo(a.y)+bflo(b.y); o0.w = bfhi(a.y)+bfhi(b.y);
    o1.x = bflo(a.z)+bflo(b.z); o1.y = bfhi(a.z)+bfhi(b.z);
    o1.z = bflo(a.w)+bflo(b.w); o1.w = bfhi(a.w)+bfhi(b.w);
    *(float4*)(out + base)     = o0;
    *(float4*)(out + base + 4) = o1;
}

extern "C" void kernel_launch(void* const* d_in, const int* in_sizes, int n_in,
                              void* d_out, int out_size, void* d_ws, size_t ws_size,
                              hipStream_t stream) {
    const float* x  = (const float*)d_in[0];
    const float* rw = (const float*)d_in[1];
    const float* W1 = (const float*)d_in[2];
    const float* W2 = (const float*)d_in[3];
    float* out = (float*)d_out;
    char* ws = (char*)d_ws;
    int*   cnt     = (int*)(ws + WS_CNT);
    int*   list    = (int*)(ws + WS_LIST);
    float* w_entry = (float*)(ws + WS_W);
    unsigned short* g  = (unsigned short*)(ws + WS_G);
    unsigned short* y  = (unsigned short*)(ws + WS_Y);
    unsigned short* xb = (unsigned short*)(ws + WS_XB);

    hipMemsetAsync(cnt, 0, E_NUM * sizeof(int), stream);
    cvt_x_kernel<<<N_TOK*H_DIM/2048, 256, 0, stream>>>(x, xb);
    router_kernel<<<N_TOK/4, 256, 0, stream>>>(x, rw, cnt, list, w_entry);
    moe_gemm_kernel<1><<<32*32*E_NUM, 256, 0, stream>>>(xb, W1, cnt, list, w_entry, g);
    moe_gemm_kernel<0><<<64*8*E_NUM, 256, 0, stream>>>(g,  W2, cnt, list, w_entry, y);
    combine_kernel<<<(out_size/8 + 255)/256, 256, 0, stream>>>(y, out);
}

// Round 9
// 225.888 us; speedup vs baseline: 1.1252x; 1.0511x over previous
//
#include <hip/hip_runtime.h>
#include <hip/hip_bf16.h>

#define H_DIM 1024
#define E_NUM 8
#define F_DIM 2048
#define N_TOK 2048   // B*S
typedef unsigned int uint;
typedef short bf16x8 __attribute__((ext_vector_type(8)));
typedef float f32x4 __attribute__((ext_vector_type(4)));

// ws layout (total ~25.3 MB)
#define WS_CNT   0
#define WS_LIST  256                       // int[8*2048]
#define WS_W     (WS_LIST + 8*N_TOK*4)     // float[4096]
#define WS_G     131072                    // bf16 [4096][2048] = 16 MB (k-PERMUTED rows)
#define WS_Y     (WS_G + 4096*2048*2)      // bf16 [4096][1024] = 8 MB
#define WS_XB    WS_Y                      // bf16 x [2048][1024] (k-PERMUTED), dead before y written

// Row k-permutation: storage position of element k is
//   pi(k) = ((k>>5)*4 + ((k>>2)&3))*8 + ((k>>4)&1)*4 + (k&3)
// block-local to every 64-k step; each 16B chunk is one MFMA A-fragment k-set.

static __device__ __forceinline__ uint f2bf(float f) {
    uint u = __builtin_bit_cast(uint, f);
    return (u + 0x7FFFu + ((u >> 16) & 1u)) >> 16;   // RNE
}
static __device__ __forceinline__ float bflo(uint u) { return __builtin_bit_cast(float, u << 16); }
static __device__ __forceinline__ float bfhi(uint u) { return __builtin_bit_cast(float, u & 0xFFFF0000u); }
static __device__ __forceinline__ uint cvtpk(float a, float b) {
    uint r;
    asm("v_cvt_pk_bf16_f32 %0, %1, %2" : "=v"(r) : "v"(a), "v"(b));  // a->low16, b->high16
    return r;
}
static __device__ __forceinline__ void gload_lds16(const void* g, void* l) {
    __builtin_amdgcn_global_load_lds(
        (const __attribute__((address_space(1))) unsigned int*)g,
        (__attribute__((address_space(3))) unsigned int*)l,
        16, 0, 0);
}
template<int N> static __device__ __forceinline__ void vmwait() {
    if constexpr (N == 0)      asm volatile("s_waitcnt vmcnt(0)" ::: "memory");
    else if constexpr (N == 4) asm volatile("s_waitcnt vmcnt(4)" ::: "memory");
    else if constexpr (N == 8) asm volatile("s_waitcnt vmcnt(8)" ::: "memory");
}

// ---------------- x -> bf16, k-permuted ----------------
__global__ __launch_bounds__(256) void cvt_x_kernel(const float* __restrict__ x,
                                                    unsigned short* __restrict__ xb)
{
    int c = blockIdx.x * 256 + threadIdx.x;
    int row = c >> 7, b = c & 127;
    int t = b >> 3, s = b & 7;
    int klo = t*64 + (s >> 2)*32 + (s & 3)*4;
    const float* xr = x + (size_t)row * H_DIM;
    float4 lo = *(const float4*)(xr + klo);
    float4 hi = *(const float4*)(xr + klo + 16);
    uint4 o;
    o.x = cvtpk(lo.x, lo.y); o.y = cvtpk(lo.z, lo.w);
    o.z = cvtpk(hi.x, hi.y); o.w = cvtpk(hi.z, hi.w);
    *(uint4*)(xb + (size_t)row * H_DIM + b*8) = o;
}

// ---------------- router ----------------
__global__ __launch_bounds__(256) void router_kernel(
    const float* __restrict__ x, const float* __restrict__ rw,
    int* __restrict__ cnt, int* __restrict__ list, float* __restrict__ w_entry)
{
    int wave = threadIdx.x >> 6, lane = threadIdx.x & 63;
    int n = blockIdx.x * 4 + wave;
    const float* xr = x + (size_t)n * H_DIM;
    float acc[8] = {0,0,0,0,0,0,0,0};
    #pragma unroll
    for (int i = 0; i < H_DIM/64; ++i) {
        int h = i*64 + lane;
        float xv = xr[h];
        const float4* rr = (const float4*)(rw + (size_t)h*8);
        float4 r0 = rr[0], r1 = rr[1];
        acc[0] += xv*r0.x; acc[1] += xv*r0.y; acc[2] += xv*r0.z; acc[3] += xv*r0.w;
        acc[4] += xv*r1.x; acc[5] += xv*r1.y; acc[6] += xv*r1.z; acc[7] += xv*r1.w;
    }
    #pragma unroll
    for (int e = 0; e < 8; ++e) {
        float v = acc[e];
        #pragma unroll
        for (int off = 32; off; off >>= 1) v += __shfl_xor(v, off);
        acc[e] = v;
    }
    int e0 = 0;
    #pragma unroll
    for (int e = 1; e < 8; ++e) if (acc[e] > acc[e0]) e0 = e;
    int e1 = -1;
    #pragma unroll
    for (int e = 0; e < 8; ++e) if (e != e0 && (e1 < 0 || acc[e] > acc[e1])) e1 = e;
    float w0 = 1.0f / (1.0f + __expf(acc[e1] - acc[e0]));
    float w1 = 1.0f - w0;
    if (lane == 0) {
        int p0 = atomicAdd(&cnt[e0], 1);
        list[e0*N_TOK + p0] = n*2;
        w_entry[n*2] = w0;
        int p1 = atomicAdd(&cnt[e1], 1);
        list[e1*N_TOK + p1] = n*2 + 1;
        w_entry[n*2+1] = w1;
    }
}

// ---------------- fused expert GEMM (counted-vmcnt, 128-row tiles) ----------------
// Both: 128x128 tile, 4 waves col-split (G1: gate blk wid / value blk 4+wid;
// G2: blks wid*2+j). A bf16 k-permuted glds, dbuf per 64k (NA=4 glds/wave).
// B fp32 glds into ((k&12)<<4)-XOR LDS (src pre-swizzled), dbuf per 32k.
// Counted waits: even vmcnt(4), odd vmcnt(8); no vmcnt(0) in loop.
template<int IS_G1>
__global__ __launch_bounds__(256, 2) void moe_gemm_kernel(
    const unsigned short* __restrict__ Asrc, const float* __restrict__ W,
    const int* __restrict__ cnt, const int* __restrict__ list,
    const float* __restrict__ w_entry, unsigned short* __restrict__ dst)
{
    constexpr int KTOT  = IS_G1 ? H_DIM : F_DIM;
    constexpr int BLD   = IS_G1 ? 2*F_DIM : H_DIM;   // W row stride (fp32)
    constexpr int DLD   = IS_G1 ? F_DIM : H_DIM;     // dst row stride
    constexpr int ALD   = IS_G1 ? H_DIM : F_DIM;     // A src row stride (shorts)
    constexpr int ROWS  = 128;
    constexpr int NM    = 8;
    constexpr int NA    = 4;                         // A glds per wave per 64k tile
    constexpr int NMT   = 16;
    constexpr int NNT   = IS_G1 ? 32 : 8;
    constexpr int NT    = KTOT / 32;                 // 32-k steps

    __shared__ __align__(16) unsigned short As[2][ROWS*64];  // 2 x 16 KB
    __shared__ __align__(16) uint Bs[2][32*128];             // 2 x 16 KB fp32 [32k][128c] swz

    constexpr int nb = NMT * NNT * E_NUM;
    constexpr int chunk = nb >> 3;
    int bid = blockIdx.x;
    int f  = (bid & 7) * chunk + (bid >> 3);
    int mt = f % NMT;
    int nt = (f / NMT) % NNT;
    int e  = f / (NMT * NNT);

    const int c = cnt[e];
    if (mt * ROWS >= c) return;
    const int tid = threadIdx.x;
    const int lane = tid & 63, wid = tid >> 6;
    const int l15 = lane & 15, lg = lane >> 4;
    const int lbase = e * N_TOK + mt * ROWS;

    // A staging sources (pre-swizzled: linear glds dest == bank-swizzled layout)
    const unsigned short* a_src[NA];
    #pragma unroll
    for (int i = 0; i < NA; ++i) {
        int sl  = wid*(NA*1024) + i*1024 + lane*16;
        int row = sl >> 7;
        int kb  = ((sl >> 4) & 7) ^ (row & 7);
        int rr  = (mt*ROWS + row) < c ? row : (c - 1 - mt*ROWS);
        int ent = list[lbase + rr];
        int arow = IS_G1 ? (ent >> 1) : ent;
        a_src[i] = Asrc + (size_t)arow * ALD + kb*8;
    }

    // B staging: wave w covers k rows w*8..+7 per 32k step; src col4 pre-XOR'd by (k&12)
    const float* Wb = W + (size_t)e * (size_t)(IS_G1 ? H_DIM*2*F_DIM : F_DIM*H_DIM);
    const float* b_srcp[4];
    #pragma unroll
    for (int i = 0; i < 4; ++i) {
        int k  = wid*8 + i*2 + (lane >> 5);
        int c4 = (lane & 31) ^ (k & 12);
        int gc;
        if constexpr (IS_G1) gc = (c4 < 16) ? (nt*64 + 4*c4) : (F_DIM + nt*64 + 4*(c4-16));
        else                 gc = nt*128 + 4*c4;
        b_srcp[i] = Wb + (size_t)k * BLD + gc;
    }

    // fragment addresses
    int a_addr[NM][2];
    #pragma unroll
    for (int m = 0; m < NM; ++m)
        #pragma unroll
        for (int p = 0; p < 2; ++p) {
            int row = m*16 + l15;
            a_addr[m][p] = row*128 + ((p*64 + lg*16) ^ ((row & 7) << 4));
        }
    int b_base[2];
    #pragma unroll
    for (int j = 0; j < 2; ++j) {
        int cb = IS_G1 ? (j ? (4 + wid) : wid) : (wid*2 + j);
        b_base[j] = ((cb*16 + l15) * 4) ^ (lg << 6);
    }

    f32x4 acc[NM][2];
    #pragma unroll
    for (int m = 0; m < NM; ++m)
        #pragma unroll
        for (int j = 0; j < 2; ++j) acc[m][j] = (f32x4){0.f,0.f,0.f,0.f};

    auto STAGE_A = [&](int s) {
        #pragma unroll
        for (int i = 0; i < NA; ++i)
            gload_lds16(a_src[i] + s*64, (char*)As[s & 1] + wid*(NA*1024) + i*1024);
    };
    auto STAGE_B = [&](int t) {
        #pragma unroll
        for (int i = 0; i < 4; ++i)
            gload_lds16(b_srcp[i] + (size_t)t * 32 * BLD, (char*)Bs[t & 1] + wid*4096 + i*1024);
    };
    auto compute = [&](int P, int abuf) {   // P literal 0/1 at call sites
        const char* ab  = (const char*)As[abuf];
        const char* bb0 = (const char*)Bs[P];
        bf16x8 bfr[2];
        #pragma unroll
        for (int j = 0; j < 2; ++j) {
            const char* bb = bb0 + (4*lg)*512 + b_base[j];
            float fA0 = *(const float*)(bb);
            float fA1 = *(const float*)(bb + 512);
            float fA2 = *(const float*)(bb + 1024);
            float fA3 = *(const float*)(bb + 1536);
            float fB0 = *(const float*)(bb + 8192);
            float fB1 = *(const float*)(bb + 8192 + 512);
            float fB2 = *(const float*)(bb + 8192 + 1024);
            float fB3 = *(const float*)(bb + 8192 + 1536);
            union { uint u[4]; bf16x8 v; } bu;
            bu.u[0] = cvtpk(fA0, fA1);
            bu.u[1] = cvtpk(fA2, fA3);
            bu.u[2] = cvtpk(fB0, fB1);
            bu.u[3] = cvtpk(fB2, fB3);
            bfr[j] = bu.v;
        }
        #pragma unroll
        for (int m = 0; m < NM; ++m) {
            bf16x8 af = *(const bf16x8*)(ab + (P ? a_addr[m][1] : a_addr[m][0]));
            #pragma unroll
            for (int j = 0; j < 2; ++j)
                acc[m][j] = __builtin_amdgcn_mfma_f32_16x16x32_bf16(af, bfr[j], acc[m][j], 0, 0, 0);
        }
    };

    // ---- prologue ----
    STAGE_A(0); STAGE_B(0); STAGE_B(1);

    // ---- main loop: pairs of 32k steps, counted waits, no vmcnt(0) ----
    for (int tp = 0; tp < NT/2 - 1; ++tp) {
        const int t = 2*tp, ab = tp & 1;
        vmwait<4>();                     // A(tp), B(t) landed; B(t+1) in flight
        __builtin_amdgcn_sched_barrier(0);
        __builtin_amdgcn_s_barrier();
        asm volatile("" ::: "memory");
        compute(0, ab);
        asm volatile("" ::: "memory");
        __builtin_amdgcn_s_barrier();
        asm volatile("" ::: "memory");
        STAGE_A(tp + 1);
        STAGE_B(t + 2);
        vmwait<8>();                     // B(t+1) landed; A(tp+1), B(t+2) in flight
        __builtin_amdgcn_sched_barrier(0);
        __builtin_amdgcn_s_barrier();
        asm volatile("" ::: "memory");
        compute(1, ab);
        asm volatile("" ::: "memory");
        __builtin_amdgcn_s_barrier();
        asm volatile("" ::: "memory");
        STAGE_B(t + 3);
    }
    // ---- final pair ----
    {
        const int ab = (NT/2 - 1) & 1;
        vmwait<4>();
        __builtin_amdgcn_sched_barrier(0);
        __builtin_amdgcn_s_barrier();
        asm volatile("" ::: "memory");
        compute(0, ab);
        asm volatile("" ::: "memory");
        vmwait<0>();
        __builtin_amdgcn_sched_barrier(0);
        __builtin_amdgcn_s_barrier();
        asm volatile("" ::: "memory");
        compute(1, ab);
    }

    // ---- epilogue (coalesced via LDS transpose; As/Bs are dead) ----
    if constexpr (IS_G1) {
        __syncthreads();
        unsigned short (*tb)[64] = (unsigned short (*)[64])As;  // 128x64 bf16 = 16 KB
        const int pcol = ((wid >> 1)*4 + (l15 >> 2))*8 + (wid & 1)*4 + (l15 & 3);
        #pragma unroll
        for (int m = 0; m < NM; ++m) {
            f32x4 ga = acc[m][0], gv = acc[m][1];
            #pragma unroll
            for (int i = 0; i < 4; ++i) {
                int row = m*16 + lg*4 + i;
                float a = ga[i];
                tb[row][pcol] = (unsigned short)f2bf((a / (1.f + __expf(-a))) * gv[i]);
            }
        }
        __syncthreads();
        int r = tid >> 1, half = tid & 1;
        if (mt*ROWS + r < c) {
            int ent = list[lbase + r];
            char* dp = (char*)dst + ((size_t)ent * DLD + nt*64)*2 + half*64;
            const char* sp = (const char*)&tb[r][0] + half*64;
            #pragma unroll
            for (int q = 0; q < 4; ++q)
                *(uint4*)(dp + q*16) = *(const uint4*)(sp + q*16);
        }
    } else {
        float (*tb)[128] = (float (*)[128])Bs;   // 32x128 f32 = 16 KB
        #pragma unroll
        for (int h = 0; h < 4; ++h) {
            __syncthreads();
            #pragma unroll
            for (int mm = 0; mm < 2; ++mm) {
                int m = h*2 + mm;
                #pragma unroll
                for (int j = 0; j < 2; ++j)
                    #pragma unroll
                    for (int i = 0; i < 4; ++i) {
                        int row = mm*16 + lg*4 + i;
                        tb[row][(wid*2 + j)*16 + l15] = acc[m][j][i];
                    }
            }
            __syncthreads();
            int r = tid >> 3, ch = tid & 7;
            int rg = h*32 + r;
            if (mt*ROWS + rg < c) {
                int ent = list[lbase + rg];
                float w = w_entry[ent];
                const float* src = &tb[r][ch*16];
                uint4 o0, o1;
                o0.x = cvtpk(w*src[0],  w*src[1]);  o0.y = cvtpk(w*src[2],  w*src[3]);
                o0.z = cvtpk(w*src[4],  w*src[5]);  o0.w = cvtpk(w*src[6],  w*src[7]);
                o1.x = cvtpk(w*src[8],  w*src[9]);  o1.y = cvtpk(w*src[10], w*src[11]);
                o1.z = cvtpk(w*src[12], w*src[13]); o1.w = cvtpk(w*src[14], w*src[15]);
                char* dp = (char*)dst + ((size_t)ent * DLD + nt*128 + ch*16)*2;
                *(uint4*)(dp)      = o0;
                *(uint4*)(dp + 16) = o1;
            }
        }
    }
}

// ---------------- combine ----------------
__global__ __launch_bounds__(256) void combine_kernel(
    const unsigned short* __restrict__ y, float* __restrict__ out)
{
    int gid = blockIdx.x * 256 + threadIdx.x;
    size_t base = (size_t)gid * 8;
    int n = (int)(base >> 10), h = (int)(base & 1023);
    const uint4 a = *(const uint4*)(y + (size_t)(2*n)   * 1024 + h);
    const uint4 b = *(const uint4*)(y + (size_t)(2*n+1) * 1024 + h);
    float4 o0, o1;
    o0.x = bflo(a.x)+bflo(b.x); o0.y = bfhi(a.x)+bfhi(b.x);
    o0.z = bflo(a.y)+bflo(b.y); o0.w = bfhi(a.y)+bfhi(b.y);
    o1.x = bflo(a.z)+bflo(b.z); o1.y = bfhi(a.z)+bfhi(b.z);
    o1.z = bflo(a.w)+bflo(b.w); o1.w = bfhi(a.w)+bfhi(b.w);
    *(float4*)(out + base)     = o0;
    *(float4*)(out + base + 4) = o1;
}

extern "C" void kernel_launch(void* const* d_in, const int* in_sizes, int n_in,
                              void* d_out, int out_size, void* d_ws, size_t ws_size,
                              hipStream_t stream) {
    const float* x  = (const float*)d_in[0];
    const float* rw = (const float*)d_in[1];
    const float* W1 = (const float*)d_in[2];
    const float* W2 = (const float*)d_in[3];
    float* out = (float*)d_out;
    char* ws = (char*)d_ws;
    int*   cnt     = (int*)(ws + WS_CNT);
    int*   list    = (int*)(ws + WS_LIST);
    float* w_entry = (float*)(ws + WS_W);
    unsigned short* g  = (unsigned short*)(ws + WS_G);
    unsigned short* y  = (unsigned short*)(ws + WS_Y);
    unsigned short* xb = (unsigned short*)(ws + WS_XB);

    hipMemsetAsync(cnt, 0, E_NUM * sizeof(int), stream);
    cvt_x_kernel<<<N_TOK*H_DIM/2048, 256, 0, stream>>>(x, xb);
    router_kernel<<<N_TOK/4, 256, 0, stream>>>(x, rw, cnt, list, w_entry);
    moe_gemm_kernel<1><<<16*32*E_NUM, 256, 0, stream>>>(xb, W1, cnt, list, w_entry, g);
    moe_gemm_kernel<0><<<16*8*E_NUM, 256, 0, stream>>>(g,  W2, cnt, list, w_entry, y);
    combine_kernel<<<(out_size/8 + 255)/256, 256, 0, stream>>>(y, out);
}

// Round 10
// 222.684 us; speedup vs baseline: 1.1414x; 1.0144x over previous
//
#include <hip/hip_runtime.h>
#include <hip/hip_bf16.h>

#define H_DIM 1024
#define E_NUM 8
#define F_DIM 2048
#define N_TOK 2048   // B*S
typedef unsigned int uint;
typedef short bf16x8 __attribute__((ext_vector_type(8)));
typedef float f32x4 __attribute__((ext_vector_type(4)));

// ws layout (total ~25.3 MB)
#define WS_CNT   0
#define WS_LIST  256                       // int[8*2048]
#define WS_W     (WS_LIST + 8*N_TOK*4)     // float[4096]
#define WS_G     131072                    // bf16 [4096][2048] = 16 MB (k-PERMUTED rows)
#define WS_Y     (WS_G + 4096*2048*2)      // bf16 [4096][1024] = 8 MB
#define WS_XB    WS_Y                      // bf16 x [2048][1024] (k-PERMUTED), dead before y written

// Row k-permutation: storage position of element k is
//   pi(k) = ((k>>5)*4 + ((k>>2)&3))*8 + ((k>>4)&1)*4 + (k&3)
// block-local to every 64-k step; each 16B chunk is one MFMA A-fragment k-set.

static __device__ __forceinline__ uint f2bf(float f) {
    uint u = __builtin_bit_cast(uint, f);
    return (u + 0x7FFFu + ((u >> 16) & 1u)) >> 16;   // RNE
}
static __device__ __forceinline__ float bflo(uint u) { return __builtin_bit_cast(float, u << 16); }
static __device__ __forceinline__ float bfhi(uint u) { return __builtin_bit_cast(float, u & 0xFFFF0000u); }
static __device__ __forceinline__ uint cvtpk(float a, float b) {
    uint r;
    asm("v_cvt_pk_bf16_f32 %0, %1, %2" : "=v"(r) : "v"(a), "v"(b));  // a->low16, b->high16
    return r;
}
static __device__ __forceinline__ void gload_lds16(const void* g, void* l) {
    __builtin_amdgcn_global_load_lds(
        (const __attribute__((address_space(1))) unsigned int*)g,
        (__attribute__((address_space(3))) unsigned int*)l,
        16, 0, 0);
}
template<int N> static __device__ __forceinline__ void vmwait() {
    if constexpr (N == 0)       asm volatile("s_waitcnt vmcnt(0)" ::: "memory");
    else if constexpr (N == 4)  asm volatile("s_waitcnt vmcnt(4)" ::: "memory");
    else if constexpr (N == 12) asm volatile("s_waitcnt vmcnt(12)" ::: "memory");
    else if constexpr (N == 16) asm volatile("s_waitcnt vmcnt(16)" ::: "memory");
}
static __device__ __forceinline__ void lgk0_bar() {
    asm volatile("s_waitcnt lgkmcnt(0)" ::: "memory");
    __builtin_amdgcn_s_barrier();
    asm volatile("" ::: "memory");
}

// ---------------- x -> bf16, k-permuted ----------------
__global__ __launch_bounds__(256) void cvt_x_kernel(const float* __restrict__ x,
                                                    unsigned short* __restrict__ xb)
{
    int c = blockIdx.x * 256 + threadIdx.x;
    int row = c >> 7, b = c & 127;
    int t = b >> 3, s = b & 7;
    int klo = t*64 + (s >> 2)*32 + (s & 3)*4;
    const float* xr = x + (size_t)row * H_DIM;
    float4 lo = *(const float4*)(xr + klo);
    float4 hi = *(const float4*)(xr + klo + 16);
    uint4 o;
    o.x = cvtpk(lo.x, lo.y); o.y = cvtpk(lo.z, lo.w);
    o.z = cvtpk(hi.x, hi.y); o.w = cvtpk(hi.z, hi.w);
    *(uint4*)(xb + (size_t)row * H_DIM + b*8) = o;
}

// ---------------- router ----------------
__global__ __launch_bounds__(256) void router_kernel(
    const float* __restrict__ x, const float* __restrict__ rw,
    int* __restrict__ cnt, int* __restrict__ list, float* __restrict__ w_entry)
{
    int wave = threadIdx.x >> 6, lane = threadIdx.x & 63;
    int n = blockIdx.x * 4 + wave;
    const float* xr = x + (size_t)n * H_DIM;
    float acc[8] = {0,0,0,0,0,0,0,0};
    #pragma unroll
    for (int i = 0; i < H_DIM/64; ++i) {
        int h = i*64 + lane;
        float xv = xr[h];
        const float4* rr = (const float4*)(rw + (size_t)h*8);
        float4 r0 = rr[0], r1 = rr[1];
        acc[0] += xv*r0.x; acc[1] += xv*r0.y; acc[2] += xv*r0.z; acc[3] += xv*r0.w;
        acc[4] += xv*r1.x; acc[5] += xv*r1.y; acc[6] += xv*r1.z; acc[7] += xv*r1.w;
    }
    #pragma unroll
    for (int e = 0; e < 8; ++e) {
        float v = acc[e];
        #pragma unroll
        for (int off = 32; off; off >>= 1) v += __shfl_xor(v, off);
        acc[e] = v;
    }
    int e0 = 0;
    #pragma unroll
    for (int e = 1; e < 8; ++e) if (acc[e] > acc[e0]) e0 = e;
    int e1 = -1;
    #pragma unroll
    for (int e = 0; e < 8; ++e) if (e != e0 && (e1 < 0 || acc[e] > acc[e1])) e1 = e;
    float w0 = 1.0f / (1.0f + __expf(acc[e1] - acc[e0]));
    float w1 = 1.0f - w0;
    if (lane == 0) {
        int p0 = atomicAdd(&cnt[e0], 1);
        list[e0*N_TOK + p0] = n*2;
        w_entry[n*2] = w0;
        int p1 = atomicAdd(&cnt[e1], 1);
        list[e1*N_TOK + p1] = n*2 + 1;
        w_entry[n*2+1] = w1;
    }
}

// ---------------- fused expert GEMM (2-pair lookahead, counted vmcnt) ----------------
// 128x128 tile, 4 waves col-split. A: bf16 k-permuted glds, 4-deep (staged 2 pairs
// ahead). B: fp32 global -> regs (2 pairs ahead, counted) -> cvtpk -> ds_write into
// verified kpair-packed bf16 Bs[2] (8 KB each). Steady queue [A,B,B,A,B,B]=24;
// vmcnt(16) twice per 64k pair; never 0 in loop. LDS 80 KB -> 2 blocks/CU.
template<int IS_G1>
__global__ __launch_bounds__(256, 2) void moe_gemm_kernel(
    const unsigned short* __restrict__ Asrc, const float* __restrict__ W,
    const int* __restrict__ cnt, const int* __restrict__ list,
    const float* __restrict__ w_entry, unsigned short* __restrict__ dst)
{
    constexpr int KTOT  = IS_G1 ? H_DIM : F_DIM;
    constexpr int BLD   = IS_G1 ? 2*F_DIM : H_DIM;   // W row stride (fp32)
    constexpr int DLD   = IS_G1 ? F_DIM : H_DIM;     // dst row stride
    constexpr int ALD   = IS_G1 ? H_DIM : F_DIM;     // A src row stride (shorts)
    constexpr int ROWS  = 128;
    constexpr int NM    = 8;
    constexpr int NA    = 4;                         // A glds per wave per 64k tile
    constexpr int NMT   = 16;
    constexpr int NNT   = IS_G1 ? 32 : 8;
    constexpr int NP    = KTOT / 64;                 // 64k pairs (16 / 32)

    __shared__ __align__(16) unsigned short As[4][ROWS*64];  // 4 x 16 KB
    __shared__ __align__(16) uint Bs[2][16*128];             // 2 x 8 KB bf16 kpair-packed

    constexpr int nb = NMT * NNT * E_NUM;
    constexpr int chunk = nb >> 3;
    int bid = blockIdx.x;
    int f  = (bid & 7) * chunk + (bid >> 3);
    int mt = f % NMT;
    int nt = (f / NMT) % NNT;
    int e  = f / (NMT * NNT);

    const int c = cnt[e];
    if (mt * ROWS >= c) return;
    const int tid = threadIdx.x;
    const int lane = tid & 63, wid = tid >> 6;
    const int l15 = lane & 15, lg = lane >> 4;
    const int lbase = e * N_TOK + mt * ROWS;

    // A staging sources (pre-swizzled: linear glds dest == bank-swizzled layout)
    const unsigned short* a_src[NA];
    #pragma unroll
    for (int i = 0; i < NA; ++i) {
        int sl  = wid*(NA*1024) + i*1024 + lane*16;
        int row = sl >> 7;
        int kb  = ((sl >> 4) & 7) ^ (row & 7);
        int rr  = (mt*ROWS + row) < c ? row : (c - 1 - mt*ROWS);
        int ent = list[lbase + rr];
        int arow = IS_G1 ? (ent >> 1) : ent;
        a_src[i] = Asrc + (size_t)arow * ALD + kb*8;
    }

    // B staging (verified R5/R6 formulas): per 32k tile, thread covers 2 chunks
    const float* Wb = W + (size_t)e * (size_t)(IS_G1 ? H_DIM*2*F_DIM : F_DIM*H_DIM);
    const float* b_src[2]; int b_dst[2];
    #pragma unroll
    for (int s = 0; s < 2; ++s) {
        int q = tid + s*256;
        int kp = q >> 5, c4 = q & 31;                // kp 0..15
        int gc;
        if constexpr (IS_G1) gc = (c4 < 16) ? (nt*64 + 4*c4) : (F_DIM + nt*64 + 4*(c4-16));
        else                 gc = nt*128 + 4*c4;
        b_src[s] = Wb + (size_t)(2*kp) * BLD + gc;
        b_dst[s] = (kp*512 + c4*16) ^ ((kp & 4) << 4);
    }

    // fragment addresses (verified)
    int a_addr[NM][2];
    #pragma unroll
    for (int m = 0; m < NM; ++m)
        #pragma unroll
        for (int p = 0; p < 2; ++p) {
            int row = m*16 + l15;
            a_addr[m][p] = row*128 + ((p*64 + lg*16) ^ ((row & 7) << 4));
        }
    int b_base[2];
    const int xorv = ((2*lg) & 4) << 4;
    #pragma unroll
    for (int j = 0; j < 2; ++j) {
        int cb = IS_G1 ? (j ? (4 + wid) : wid) : (wid*2 + j);
        b_base[j] = (2*lg)*512 + (((cb*16 + l15) * 4) ^ xorv);
    }

    f32x4 acc[NM][2];
    #pragma unroll
    for (int m = 0; m < NM; ++m)
        #pragma unroll
        for (int j = 0; j < 2; ++j) acc[m][j] = (f32x4){0.f,0.f,0.f,0.f};

    struct BQ { float4 a0, a1, b0, b1; };
    auto loadB = [&](int t) {
        BQ q;
        const float* p0 = b_src[0] + (size_t)t * 32 * BLD;
        q.a0 = *(const float4*)p0;
        q.a1 = *(const float4*)(p0 + BLD);
        const float* p1 = b_src[1] + (size_t)t * 32 * BLD;
        q.b0 = *(const float4*)p1;
        q.b1 = *(const float4*)(p1 + BLD);
        return q;
    };
    auto dswB = [&](const BQ& q, int buf) {
        uint4 w0, w1;
        w0.x = cvtpk(q.a0.x, q.a1.x); w0.y = cvtpk(q.a0.y, q.a1.y);
        w0.z = cvtpk(q.a0.z, q.a1.z); w0.w = cvtpk(q.a0.w, q.a1.w);
        w1.x = cvtpk(q.b0.x, q.b1.x); w1.y = cvtpk(q.b0.y, q.b1.y);
        w1.z = cvtpk(q.b0.z, q.b1.z); w1.w = cvtpk(q.b0.w, q.b1.w);
        *(uint4*)((char*)Bs[buf] + b_dst[0]) = w0;
        *(uint4*)((char*)Bs[buf] + b_dst[1]) = w1;
    };
    auto STAGE_A = [&](int s) {
        #pragma unroll
        for (int i = 0; i < NA; ++i)
            gload_lds16(a_src[i] + s*64, (char*)As[s & 3] + wid*(NA*1024) + i*1024);
    };
    auto compute = [&](int P, int abuf) {            // P literal at call sites
        const char* ab  = (const char*)As + abuf*(ROWS*128);
        const char* bb0 = (const char*)Bs[P];
        bf16x8 bfr[2];
        #pragma unroll
        for (int j = 0; j < 2; ++j) {
            const char* bb = bb0 + b_base[j];
            union { uint u[4]; bf16x8 v; } bu;
            bu.u[0] = *(const uint*)(bb);
            bu.u[1] = *(const uint*)(bb + 512);
            bu.u[2] = *(const uint*)(bb + 8*512);
            bu.u[3] = *(const uint*)(bb + 9*512);
            bfr[j] = bu.v;
        }
        #pragma unroll
        for (int m = 0; m < NM; ++m) {
            bf16x8 af = *(const bf16x8*)(ab + (P ? a_addr[m][1] : a_addr[m][0]));
            #pragma unroll
            for (int j = 0; j < 2; ++j)
                acc[m][j] = __builtin_amdgcn_mfma_f32_16x16x32_bf16(af, bfr[j], acc[m][j], 0, 0, 0);
        }
    };

    // ---- prologue: queue order [A0, B0, B1, A1, B2, B3] = 24 in flight ----
    STAGE_A(0);
    BQ q0 = loadB(0);
    BQ q1 = loadB(1);
    STAGE_A(1);
    BQ q2 = loadB(2);
    BQ q3 = loadB(3);

    // ---- steady loop: 2 pairs per iteration, vmcnt(16) throughout ----
    for (int tp = 0; tp < NP - 2; tp += 2) {
        const int t = 2*tp;
        // pair tp (consumes q0,q1)
        vmwait<16>(); __builtin_amdgcn_sched_barrier(0);
        dswB(q0, 0);
        lgk0_bar();
        STAGE_A(tp + 2);
        compute(0, tp & 3);
        vmwait<16>(); __builtin_amdgcn_sched_barrier(0);
        dswB(q1, 1);
        lgk0_bar();
        q0 = loadB(t + 4);
        q1 = loadB(t + 5);
        compute(1, tp & 3);
        // pair tp+1 (consumes q2,q3)
        vmwait<16>(); __builtin_amdgcn_sched_barrier(0);
        dswB(q2, 0);
        lgk0_bar();
        STAGE_A(tp + 3);
        compute(0, (tp + 1) & 3);
        vmwait<16>(); __builtin_amdgcn_sched_barrier(0);
        dswB(q3, 1);
        lgk0_bar();
        q2 = loadB(t + 6);
        q3 = loadB(t + 7);
        compute(1, (tp + 1) & 3);
    }
    // ---- tail: pairs NP-2, NP-1 (no new issues) ----
    {
        vmwait<16>(); __builtin_amdgcn_sched_barrier(0);
        dswB(q0, 0);
        lgk0_bar();
        compute(0, (NP - 2) & 3);
        vmwait<12>(); __builtin_amdgcn_sched_barrier(0);
        dswB(q1, 1);
        lgk0_bar();
        compute(1, (NP - 2) & 3);
        vmwait<4>(); __builtin_amdgcn_sched_barrier(0);
        dswB(q2, 0);
        lgk0_bar();
        compute(0, (NP - 1) & 3);
        vmwait<0>(); __builtin_amdgcn_sched_barrier(0);
        dswB(q3, 1);
        lgk0_bar();
        compute(1, (NP - 1) & 3);
    }

    // ---- epilogue (coalesced via LDS transpose in As; verified R9 forms) ----
    if constexpr (IS_G1) {
        __syncthreads();
        unsigned short (*tb)[64] = (unsigned short (*)[64])As;  // 128x64 bf16 = 16 KB
        const int pcol = ((wid >> 1)*4 + (l15 >> 2))*8 + (wid & 1)*4 + (l15 & 3);
        #pragma unroll
        for (int m = 0; m < NM; ++m) {
            f32x4 ga = acc[m][0], gv = acc[m][1];
            #pragma unroll
            for (int i = 0; i < 4; ++i) {
                int row = m*16 + lg*4 + i;
                float a = ga[i];
                tb[row][pcol] = (unsigned short)f2bf((a / (1.f + __expf(-a))) * gv[i]);
            }
        }
        __syncthreads();
        int r = tid >> 1, half = tid & 1;
        if (mt*ROWS + r < c) {
            int ent = list[lbase + r];
            char* dp = (char*)dst + ((size_t)ent * DLD + nt*64)*2 + half*64;
            const char* sp = (const char*)&tb[r][0] + half*64;
            #pragma unroll
            for (int qq = 0; qq < 4; ++qq)
                *(uint4*)(dp + qq*16) = *(const uint4*)(sp + qq*16);
        }
    } else {
        float (*tb)[128] = (float (*)[128])As;   // 32x128 f32 = 16 KB
        #pragma unroll
        for (int h = 0; h < 4; ++h) {
            __syncthreads();
            #pragma unroll
            for (int mm = 0; mm < 2; ++mm) {
                int m = h*2 + mm;
                #pragma unroll
                for (int j = 0; j < 2; ++j)
                    #pragma unroll
                    for (int i = 0; i < 4; ++i) {
                        int row = mm*16 + lg*4 + i;
                        tb[row][(wid*2 + j)*16 + l15] = acc[m][j][i];
                    }
            }
            __syncthreads();
            int r = tid >> 3, ch = tid & 7;
            int rg = h*32 + r;
            if (mt*ROWS + rg < c) {
                int ent = list[lbase + rg];
                float w = w_entry[ent];
                const float* src = &tb[r][ch*16];
                uint4 o0, o1;
                o0.x = cvtpk(w*src[0],  w*src[1]);  o0.y = cvtpk(w*src[2],  w*src[3]);
                o0.z = cvtpk(w*src[4],  w*src[5]);  o0.w = cvtpk(w*src[6],  w*src[7]);
                o1.x = cvtpk(w*src[8],  w*src[9]);  o1.y = cvtpk(w*src[10], w*src[11]);
                o1.z = cvtpk(w*src[12], w*src[13]); o1.w = cvtpk(w*src[14], w*src[15]);
                char* dp = (char*)dst + ((size_t)ent * DLD + nt*128 + ch*16)*2;
                *(uint4*)(dp)      = o0;
                *(uint4*)(dp + 16) = o1;
            }
        }
    }
}

// ---------------- combine ----------------
__global__ __launch_bounds__(256) void combine_kernel(
    const unsigned short* __restrict__ y, float* __restrict__ out)
{
    int gid = blockIdx.x * 256 + threadIdx.x;
    size_t base = (size_t)gid * 8;
    int n = (int)(base >> 10), h = (int)(base & 1023);
    const uint4 a = *(const uint4*)(y + (size_t)(2*n)   * 1024 + h);
    const uint4 b = *(const uint4*)(y + (size_t)(2*n+1) * 1024 + h);
    float4 o0, o1;
    o0.x = bflo(a.x)+bflo(b.x); o0.y = bfhi(a.x)+bfhi(b.x);
    o0.z = bflo(a.y)+bflo(b.y); o0.w = bfhi(a.y)+bfhi(b.y);
    o1.x = bflo(a.z)+bflo(b.z); o1.y = bfhi(a.z)+bfhi(b.z);
    o1.z = bflo(a.w)+bflo(b.w); o1.w = bfhi(a.w)+bfhi(b.w);
    *(float4*)(out + base)     = o0;
    *(float4*)(out + base + 4) = o1;
}

extern "C" void kernel_launch(void* const* d_in, const int* in_sizes, int n_in,
                              void* d_out, int out_size, void* d_ws, size_t ws_size,
                              hipStream_t stream) {
    const float* x  = (const float*)d_in[0];
    const float* rw = (const float*)d_in[1];
    const float* W1 = (const float*)d_in[2];
    const float* W2 = (const float*)d_in[3];
    float* out = (float*)d_out;
    char* ws = (char*)d_ws;
    int*   cnt     = (int*)(ws + WS_CNT);
    int*   list    = (int*)(ws + WS_LIST);
    float* w_entry = (float*)(ws + WS_W);
    unsigned short* g  = (unsigned short*)(ws + WS_G);
    unsigned short* y  = (unsigned short*)(ws + WS_Y);
    unsigned short* xb = (unsigned short*)(ws + WS_XB);

    hipMemsetAsync(cnt, 0, E_NUM * sizeof(int), stream);
    cvt_x_kernel<<<N_TOK*H_DIM/2048, 256, 0, stream>>>(x, xb);
    router_kernel<<<N_TOK/4, 256, 0, stream>>>(x, rw, cnt, list, w_entry);
    moe_gemm_kernel<1><<<16*32*E_NUM, 256, 0, stream>>>(xb, W1, cnt, list, w_entry, g);
    moe_gemm_kernel<0><<<16*8*E_NUM, 256, 0, stream>>>(g,  W2, cnt, list, w_entry, y);
    combine_kernel<<<(out_size/8 + 255)/256, 256, 0, stream>>>(y, out);
}